// Round 1
// baseline (1388.052 us; speedup 1.0000x reference)
//
#include <hip/hip_runtime.h>
#include <hip/hip_bf16.h>
#include <math.h>

typedef __bf16 bf16;
typedef __bf16 bf16x8 __attribute__((ext_vector_type(8)));
typedef __bf16 bf16x4 __attribute__((ext_vector_type(4)));
typedef float  f32x4  __attribute__((ext_vector_type(4)));

#define DEV __device__ __forceinline__

DEV f32x4 mfma16(bf16x8 a, bf16x8 b, f32x4 c) {
    return __builtin_amdgcn_mfma_f32_16x16x32_bf16(a, b, c, 0, 0, 0);
}

// async 16B global->LDS. LDS dest is wave-uniform base + lane*16 (linear!).
DEV void gload16(const bf16* g, bf16* l) {
    __builtin_amdgcn_global_load_lds(
        (const __attribute__((address_space(1))) void*)g,
        (__attribute__((address_space(3))) void*)l, 16, 0, 0);
}

// ---------------------------------------------------------------------------
// Wide GEMM: C[M x N] = A[M x K] @ Bt[N x K]^T (+fp32 bias), 128x128, BK=32.
// Staging via global_load_lds width=16 (m97 structure). Chunk-XOR swizzle is
// pre-applied to the GLOBAL source address; LDS dest stays linear; reads use
// the same XOR (both-sides rule) -> LDS contents identical to the old
// reg-staged version (conflict-free reads preserved).
// MODE 1: Cb = gelu(acc + bias), ldC layout.
// MODE 2 (QKV): cols <1024 (Q,K) -> Cb[ldC]; cols >=1024 (V) -> vt in
//               transposed [(b*8+h)*64+d][n] layout (8B packed stores).
// ---------------------------------------------------------------------------
template <int MODE>
__global__ __launch_bounds__(256, 3) void gemm_k(
    const bf16* __restrict__ A, const bf16* __restrict__ Bt,
    const float* __restrict__ bias, bf16* __restrict__ Cb,
    bf16* __restrict__ vt, int K, int ldC)
{
    __shared__ bf16 As[128 * 32];
    __shared__ bf16 Bs[128 * 32];
    const int tid  = threadIdx.x;
    const int lane = tid & 63;
    const int w    = tid >> 6;
    const int wm   = w & 1, wn = w >> 1;
    const long tm  = (long)blockIdx.y * 128;
    const long tn  = (long)blockIdx.x * 128;

    f32x4 acc[4][4] = {};

    // linear LDS slot = tid (row tid>>2, 16B-chunk tid&3); source chunk XOR'd
    const int r0 = tid >> 2;                          // 0..63 (row; +64 for slot tid+256)
    const int cc = ((tid & 3) ^ ((r0 >> 1) & 3)) * 8; // (r+64)>>1 & 3 == (r>>1)&3
    const bf16* Ag = A  + (tm + r0) * K + cc;
    const bf16* Bg = Bt + (tn + r0) * K + cc;
    const long rstep = (long)64 * K;
    bf16* lA0 = &As[tid * 8];
    bf16* lA1 = &As[(tid + 256) * 8];
    bf16* lB0 = &Bs[tid * 8];
    bf16* lB1 = &Bs[(tid + 256) * 8];

    int am[4], bn[4];
#pragma unroll
    for (int i = 0; i < 4; ++i) {
        int ra = wm * 64 + i * 16 + (lane & 15);
        am[i]  = ra * 32 + (((lane >> 4) ^ ((ra >> 1) & 3)) * 8);
        int rb = wn * 64 + i * 16 + (lane & 15);
        bn[i]  = rb * 32 + (((lane >> 4) ^ ((rb >> 1) & 3)) * 8);
    }

    for (int k0 = 0; k0 < K; k0 += 32) {
        __syncthreads();                 // prev tile fully consumed
        gload16(Ag + k0,         lA0);
        gload16(Ag + rstep + k0, lA1);
        gload16(Bg + k0,         lB0);
        gload16(Bg + rstep + k0, lB1);
        __syncthreads();                 // compiler drains vmcnt(0) here
        bf16x8 a[4], b[4];
#pragma unroll
        for (int i = 0; i < 4; ++i) a[i] = *(const bf16x8*)&As[am[i]];
#pragma unroll
        for (int i = 0; i < 4; ++i) b[i] = *(const bf16x8*)&Bs[bn[i]];
#pragma unroll
        for (int mi = 0; mi < 4; ++mi)
#pragma unroll
            for (int ni = 0; ni < 4; ++ni)
                acc[mi][ni] = mfma16(a[mi], b[ni], acc[mi][ni]);
    }

#pragma unroll
    for (int mi = 0; mi < 4; ++mi) {
        const long rbase = tm + wm * 64 + mi * 16 + ((lane >> 4) << 2);
#pragma unroll
        for (int ni = 0; ni < 4; ++ni) {
            const long col = tn + wn * 64 + ni * 16 + (lane & 15);
            const float bv = bias[col];
            float v[4];
#pragma unroll
            for (int r = 0; r < 4; ++r) {
                v[r] = acc[mi][ni][r] + bv;
                if constexpr (MODE == 1)
                    v[r] = 0.5f * v[r] * (1.0f + erff(v[r] * 0.70710678118654752f));
            }
            bool toV = false;
            if constexpr (MODE == 2) toV = (col >= 1024);
            if (toV) {
                // V^T: vt[((b*8+h)*64 + d)*256 + n], 4 consecutive n -> 8B store
                const int cv = (int)col - 1024;
                const long bh = (rbase >> 8) * 8 + (cv >> 6);
                bf16x4 pk;
#pragma unroll
                for (int r = 0; r < 4; ++r) pk[r] = (bf16)v[r];
                *(bf16x4*)&vt[(bh * 64 + (cv & 63)) * 256 + (rbase & 255)] = pk;
            } else {
#pragma unroll
                for (int r = 0; r < 4; ++r)
                    Cb[(rbase + r) * (long)ldC + col] = (bf16)v[r];
            }
        }
    }
}

// ---------------------------------------------------------------------------
// Split-K delta GEMM for proj/FFN2 (N=512): same global_load_lds staging.
// Writes bf16 delta slice; residual-add in the fused LN consuming the slices.
// ---------------------------------------------------------------------------
__global__ __launch_bounds__(256, 3) void gemm_dk(
    const bf16* __restrict__ A, const bf16* __restrict__ Bt,
    bf16* __restrict__ D, int K, int Ks)
{
    __shared__ bf16 As[128 * 32];
    __shared__ bf16 Bs[128 * 32];
    const int tid  = threadIdx.x;
    const int lane = tid & 63;
    const int w    = tid >> 6;
    const int wm   = w & 1, wn = w >> 1;
    const long tm  = (long)blockIdx.y * 128;
    const long tn  = (long)blockIdx.x * 128;
    const int kbase = blockIdx.z * Ks;

    f32x4 acc[4][4] = {};

    const int r0 = tid >> 2;
    const int cc = ((tid & 3) ^ ((r0 >> 1) & 3)) * 8;
    const bf16* Ag = A  + (tm + r0) * K + kbase + cc;
    const bf16* Bg = Bt + (tn + r0) * K + kbase + cc;
    const long rstep = (long)64 * K;
    bf16* lA0 = &As[tid * 8];
    bf16* lA1 = &As[(tid + 256) * 8];
    bf16* lB0 = &Bs[tid * 8];
    bf16* lB1 = &Bs[(tid + 256) * 8];

    int am[4], bn[4];
#pragma unroll
    for (int i = 0; i < 4; ++i) {
        int ra = wm * 64 + i * 16 + (lane & 15);
        am[i]  = ra * 32 + (((lane >> 4) ^ ((ra >> 1) & 3)) * 8);
        int rb = wn * 64 + i * 16 + (lane & 15);
        bn[i]  = rb * 32 + (((lane >> 4) ^ ((rb >> 1) & 3)) * 8);
    }

    for (int k0 = 0; k0 < Ks; k0 += 32) {
        __syncthreads();
        gload16(Ag + k0,         lA0);
        gload16(Ag + rstep + k0, lA1);
        gload16(Bg + k0,         lB0);
        gload16(Bg + rstep + k0, lB1);
        __syncthreads();
        bf16x8 a[4], b[4];
#pragma unroll
        for (int i = 0; i < 4; ++i) a[i] = *(const bf16x8*)&As[am[i]];
#pragma unroll
        for (int i = 0; i < 4; ++i) b[i] = *(const bf16x8*)&Bs[bn[i]];
#pragma unroll
        for (int mi = 0; mi < 4; ++mi)
#pragma unroll
            for (int ni = 0; ni < 4; ++ni)
                acc[mi][ni] = mfma16(a[mi], b[ni], acc[mi][ni]);
    }

    bf16* Dp = D + (long)blockIdx.z * 8192 * 512;
#pragma unroll
    for (int mi = 0; mi < 4; ++mi) {
        const long rbase = tm + wm * 64 + mi * 16 + ((lane >> 4) << 2);
#pragma unroll
        for (int ni = 0; ni < 4; ++ni) {
            const long col = tn + wn * 64 + ni * 16 + (lane & 15);
#pragma unroll
            for (int r = 0; r < 4; ++r)
                Dp[(rbase + r) * 512 + col] = (bf16)acc[mi][ni][r];
        }
    }
}

// ---------------------------------------------------------------------------
// Attention: one block per (b, h, 64-row q tile).
// V is consumed directly from the pre-transposed global vt (written by the
// QKV GEMM) -> no V LDS staging, no scalar transpose loads, LDS 53.8->36.9KB
// (4 blocks/CU instead of 2).
// ---------------------------------------------------------------------------
__global__ __launch_bounds__(256, 4) void attn_k(
    const bf16* __restrict__ qkv, const bf16* __restrict__ vt,
    const float* __restrict__ bias, bf16* __restrict__ ctx)
{
    __shared__ bf16 smem[256 * 72];
    bf16* Ks = smem;

    const int tid = threadIdx.x, lane = tid & 63, w = tid >> 6;
    const int qt = blockIdx.x & 3;
    const int h  = (blockIdx.x >> 2) & 7;
    const int b  = blockIdx.x >> 5;
    const long qkv_base = (long)b * 256 * 1536;

#pragma unroll
    for (int i = 0; i < 8; ++i) {
        int p = i * 256 + tid;
        int n = p >> 3, kk = (p & 7) * 8;
        uint4 v = *(const uint4*)(qkv + qkv_base + (long)n * 1536 + 512 + h * 64 + kk);
        *(uint4*)&Ks[n * 72 + kk] = v;
    }

    const int qr0 = qt * 64 + w * 16;
    bf16x8 aq0, aq1;
    {
        const bf16* g = qkv + qkv_base + (long)(qr0 + (lane & 15)) * 1536 + h * 64 + ((lane >> 4) * 8);
        aq0 = *(const bf16x8*)g;
        aq1 = *(const bf16x8*)(g + 32);
    }
    __syncthreads();

    f32x4 s[16];
    const float* bb = bias + (((long)(b * 8 + h)) * 256 + qr0) * 256;
#pragma unroll
    for (int ct = 0; ct < 16; ++ct) {
        const int col = ct * 16 + (lane & 15);
        f32x4 c;
#pragma unroll
        for (int r = 0; r < 4; ++r)
            c[r] = bb[(long)((lane >> 4) * 4 + r) * 256 + col];
        bf16x8 k0 = *(const bf16x8*)&Ks[(ct * 16 + (lane & 15)) * 72 + ((lane >> 4) * 8)];
        bf16x8 k1 = *(const bf16x8*)&Ks[(ct * 16 + (lane & 15)) * 72 + 32 + ((lane >> 4) * 8)];
        c = mfma16(aq0, k0, c);
        c = mfma16(aq1, k1, c);
        s[ct] = c;
    }

    float m[4] = {-1e30f, -1e30f, -1e30f, -1e30f};
#pragma unroll
    for (int ct = 0; ct < 16; ++ct)
#pragma unroll
        for (int r = 0; r < 4; ++r) m[r] = fmaxf(m[r], s[ct][r]);
#pragma unroll
    for (int r = 0; r < 4; ++r)
#pragma unroll
        for (int off = 1; off < 16; off <<= 1)
            m[r] = fmaxf(m[r], __shfl_xor(m[r], off));
    float l[4] = {0.f, 0.f, 0.f, 0.f};
#pragma unroll
    for (int ct = 0; ct < 16; ++ct)
#pragma unroll
        for (int r = 0; r < 4; ++r) {
            float p = __expf(s[ct][r] - m[r]);
            s[ct][r] = p;
            l[r] += p;
        }
#pragma unroll
    for (int r = 0; r < 4; ++r) {
#pragma unroll
        for (int off = 1; off < 16; off <<= 1) l[r] += __shfl_xor(l[r], off);
        l[r] = 1.0f / l[r];
    }

    __syncthreads();
    bf16* P = smem + w * (16 * 264);
#pragma unroll
    for (int ct = 0; ct < 16; ++ct)
#pragma unroll
        for (int r = 0; r < 4; ++r)
            P[(long)((lane >> 4) * 4 + r) * 264 + ct * 16 + (lane & 15)] = (bf16)s[ct][r];

    bf16x8 ap[8];
#pragma unroll
    for (int nk = 0; nk < 8; ++nk)
        ap[nk] = *(const bf16x8*)&P[(lane & 15) * 264 + nk * 32 + (lane >> 4) * 8];

    const bf16* vg = vt + (long)(b * 8 + h) * 64 * 256;
    f32x4 o[4];
#pragma unroll
    for (int dt = 0; dt < 4; ++dt) {
        f32x4 c = {};
#pragma unroll
        for (int nk = 0; nk < 8; ++nk) {
            bf16x8 bv = *(const bf16x8*)&vg[(dt * 16 + (lane & 15)) * 256 + nk * 32 + (lane >> 4) * 8];
            c = mfma16(ap[nk], bv, c);
        }
        o[dt] = c;
    }

#pragma unroll
    for (int dt = 0; dt < 4; ++dt) {
        const int col = h * 64 + dt * 16 + (lane & 15);
#pragma unroll
        for (int r = 0; r < 4; ++r) {
            const long row = (long)b * 256 + qr0 + (lane >> 4) * 4 + r;
            ctx[row * 512 + col] = (bf16)(o[dt][r] * l[r]);
        }
    }
}

// ---------------------------------------------------------------------------
// Fused residual-add + LayerNorm. NS = number of bf16 delta slices (0 or 2).
// ---------------------------------------------------------------------------
template <int NS>
__global__ __launch_bounds__(256) void ln_k(
    const float* __restrict__ x, float* __restrict__ xout,
    const bf16* __restrict__ d, const float* __restrict__ rbias,
    const float* __restrict__ sc, const float* __restrict__ bi,
    bf16* __restrict__ y)
{
    const int lane = threadIdx.x & 63;
    const long row = (long)blockIdx.x * 4 + (threadIdx.x >> 6);
    const float* xr = x + row * 512;
    float v[8];
    *(float4*)&v[0] = ((const float4*)xr)[lane * 2];
    *(float4*)&v[4] = ((const float4*)xr)[lane * 2 + 1];
    if constexpr (NS == 2) {
        bf16x8 d0 = *(const bf16x8*)&d[row * 512 + lane * 8];
        bf16x8 d1 = *(const bf16x8*)&d[(long)8192 * 512 + row * 512 + lane * 8];
        float b4[8];
        *(float4*)&b4[0] = ((const float4*)rbias)[lane * 2];
        *(float4*)&b4[4] = ((const float4*)rbias)[lane * 2 + 1];
#pragma unroll
        for (int j = 0; j < 8; ++j)
            v[j] += (float)d0[j] + (float)d1[j] + b4[j];
        float* xo = xout + row * 512;
        ((float4*)xo)[lane * 2]     = *(const float4*)&v[0];
        ((float4*)xo)[lane * 2 + 1] = *(const float4*)&v[4];
    }
    float sum = 0.f;
#pragma unroll
    for (int j = 0; j < 8; ++j) sum += v[j];
#pragma unroll
    for (int off = 1; off < 64; off <<= 1) sum += __shfl_xor(sum, off);
    const float mu = sum * (1.0f / 512.0f);
    float sq = 0.f;
#pragma unroll
    for (int j = 0; j < 8; ++j) { float dd = v[j] - mu; sq += dd * dd; }
#pragma unroll
    for (int off = 1; off < 64; off <<= 1) sq += __shfl_xor(sq, off);
    const float rs = rsqrtf(sq * (1.0f / 512.0f) + 1e-5f);
    bf16* yr = y + row * 512;
#pragma unroll
    for (int j = 0; j < 8; ++j) {
        int c = lane * 8 + j;
        yr[c] = (bf16)((v[j] - mu) * rs * sc[c] + bi[c]);
    }
}

// final: out = xf + d0 + d1 + rbias (fp32)
__global__ __launch_bounds__(256) void addout_k(
    const float* __restrict__ x, const bf16* __restrict__ d,
    const float* __restrict__ rbias, float* __restrict__ out)
{
    const int lane = threadIdx.x & 63;
    const long row = (long)blockIdx.x * 4 + (threadIdx.x >> 6);
    float v[8];
    *(float4*)&v[0] = ((const float4*)(x + row * 512))[lane * 2];
    *(float4*)&v[4] = ((const float4*)(x + row * 512))[lane * 2 + 1];
    bf16x8 d0 = *(const bf16x8*)&d[row * 512 + lane * 8];
    bf16x8 d1 = *(const bf16x8*)&d[(long)8192 * 512 + row * 512 + lane * 8];
    float b4[8];
    *(float4*)&b4[0] = ((const float4*)rbias)[lane * 2];
    *(float4*)&b4[4] = ((const float4*)rbias)[lane * 2 + 1];
#pragma unroll
    for (int j = 0; j < 8; ++j)
        v[j] += (float)d0[j] + (float)d1[j] + b4[j];
    float* o = out + row * 512;
    ((float4*)o)[lane * 2]     = *(const float4*)&v[0];
    ((float4*)o)[lane * 2 + 1] = *(const float4*)&v[4];
}

// ---------------------------------------------------------------------------
// One-shot weight transpose fp32 -> bf16 [N][K] layout (q-scale folded).
// ---------------------------------------------------------------------------
__global__ __launch_bounds__(256) void transpose_k(
    const float* __restrict__ wq, const float* __restrict__ wk,
    const float* __restrict__ wv, const float* __restrict__ wo,
    const float* __restrict__ w1, const float* __restrict__ w2,
    bf16* __restrict__ qkvT, bf16* __restrict__ woT,
    bf16* __restrict__ w1T, bf16* __restrict__ w2T)
{
    __shared__ float tile[32][33];
    const int tid = threadIdx.x, tx = tid & 31, ty = tid >> 5;
    const int l = blockIdx.x / 3072;
    const int r = blockIdx.x % 3072;

    const float* In = nullptr;
    bf16* Out = nullptr;
    int Nd, tk, tn, rowOff = 0, ldO;
    float scale = 1.0f;
    if (r < 1024) {
        const int which = r >> 8, t = r & 255;
        tn = t >> 4; tk = t & 15; Nd = 512; ldO = 512;
        const long woff = (long)l * 512 * 512;
        if (which == 0)      { In = wq + woff; Out = qkvT + (long)l * 1536 * 512; rowOff = 0;    scale = 0.125f; }
        else if (which == 1) { In = wk + woff; Out = qkvT + (long)l * 1536 * 512; rowOff = 512;  }
        else if (which == 2) { In = wv + woff; Out = qkvT + (long)l * 1536 * 512; rowOff = 1024; }
        else                 { In = wo + woff; Out = woT + woff; }
    } else if (r < 2048) {
        const int t = r - 1024;
        tn = t >> 4; tk = t & 15; Nd = 2048; ldO = 512;
        In = w1 + (long)l * 512 * 2048; Out = w1T + (long)l * 2048 * 512;
    } else {
        const int t = r - 2048;
        tn = t & 15; tk = t >> 4; Nd = 512; ldO = 2048;
        In = w2 + (long)l * 2048 * 512; Out = w2T + (long)l * 512 * 2048;
    }
    const int gk = tk * 32, gn = tn * 32;
#pragma unroll
    for (int j = 0; j < 4; ++j) {
        int rr = ty + j * 8;
        tile[rr][tx] = In[(long)(gk + rr) * Nd + gn + tx] * scale;
    }
    __syncthreads();
#pragma unroll
    for (int j = 0; j < 4; ++j) {
        int rr = ty + j * 8;
        Out[(long)(rowOff + gn + rr) * ldO + gk + tx] = (bf16)tile[tx][rr];
    }
}

__global__ void biasq_k(const float* __restrict__ bq, const float* __restrict__ bk,
                        const float* __restrict__ bv, float* __restrict__ bqkv)
{
    int i = blockIdx.x * 256 + threadIdx.x;
    if (i >= 8 * 1536) return;
    int l = i / 1536, j = i % 1536;
    float v;
    if (j < 512)       v = bq[l * 512 + j] * 0.125f;
    else if (j < 1024) v = bk[l * 512 + j - 512];
    else               v = bv[l * 512 + j - 1024];
    bqkv[i] = v;
}

// ---------------------------------------------------------------------------
extern "C" void kernel_launch(void* const* d_in, const int* in_sizes, int n_in,
                              void* d_out, int out_size, void* d_ws, size_t ws_size,
                              hipStream_t stream)
{
    (void)in_sizes; (void)n_in; (void)out_size; (void)ws_size;
    const float* x    = (const float*)d_in[0];
    const float* ab   = (const float*)d_in[1];
    const float* ln1s = (const float*)d_in[2];
    const float* ln1b = (const float*)d_in[3];
    const float* wq   = (const float*)d_in[4];
    const float* bq   = (const float*)d_in[5];
    const float* wk   = (const float*)d_in[6];
    const float* bk   = (const float*)d_in[7];
    const float* wv   = (const float*)d_in[8];
    const float* bv   = (const float*)d_in[9];
    const float* wo   = (const float*)d_in[10];
    const float* bo   = (const float*)d_in[11];
    const float* ln2s = (const float*)d_in[12];
    const float* ln2b = (const float*)d_in[13];
    const float* w1   = (const float*)d_in[14];
    const float* b1   = (const float*)d_in[15];
    const float* w2   = (const float*)d_in[16];
    const float* b2   = (const float*)d_in[17];

    char* ws = (char*)d_ws;
    // [0,16M) xf fp32 | [16M,24M) y/ctx bf16 | [24M,56M) qkv(25.2M)+vt(8.4M)/ffn bf16
    // [56M,72M) delta bf16 [2][8192][512] | [72M,~120M) weights + bqkv
    float* xf   = (float*)ws;
    bf16* y     = (bf16*)(ws + 16777216);
    bf16* ctx   = y;
    bf16* qkv   = (bf16*)(ws + 16777216 + 8388608);
    bf16* ffn   = qkv;
    bf16* vt    = qkv + (long)8192 * 1536;   // tail of the 32M region; dead once FFN1 runs
    bf16* dbuf  = (bf16*)(ws + 16777216 + 8388608 + 33554432);
    bf16* wqkvT = dbuf + (long)2 * 8192 * 512;
    bf16* woT   = wqkvT + (long)8 * 1536 * 512;
    bf16* w1T   = woT + (long)8 * 512 * 512;
    bf16* w2T   = w1T + (long)8 * 2048 * 512;
    float* bqkv = (float*)(w2T + (long)8 * 512 * 2048);

    hipMemcpyAsync(xf, x, (size_t)8192 * 512 * 4, hipMemcpyDeviceToDevice, stream);
    transpose_k<<<24576, 256, 0, stream>>>(wq, wk, wv, wo, w1, w2, wqkvT, woT, w1T, w2T);
    biasq_k<<<48, 256, 0, stream>>>(bq, bk, bv, bqkv);

    for (int l = 0; l < 8; ++l) {
        if (l == 0)
            ln_k<0><<<2048, 256, 0, stream>>>(xf, nullptr, nullptr, nullptr,
                                              ln1s, ln1b, y);
        else
            ln_k<2><<<2048, 256, 0, stream>>>(xf, xf, dbuf, b2 + (l - 1) * 512,
                                              ln1s + l * 512, ln1b + l * 512, y);
        gemm_k<2><<<dim3(12, 64), 256, 0, stream>>>(
            y, wqkvT + (long)l * 1536 * 512, bqkv + l * 1536, qkv, vt, 512, 1536);
        attn_k<<<1024, 256, 0, stream>>>(qkv, vt, ab, ctx);
        gemm_dk<<<dim3(4, 64, 2), 256, 0, stream>>>(
            ctx, woT + (long)l * 512 * 512, dbuf, 512, 256);
        ln_k<2><<<2048, 256, 0, stream>>>(xf, xf, dbuf, bo + l * 512,
                                          ln2s + l * 512, ln2b + l * 512, y);
        gemm_k<1><<<dim3(16, 64), 256, 0, stream>>>(
            y, w1T + (long)l * 2048 * 512, b1 + l * 2048, ffn, nullptr, 512, 2048);
        gemm_dk<<<dim3(4, 64, 2), 256, 0, stream>>>(
            ffn, w2T + (long)l * 512 * 2048, dbuf, 2048, 1024);
    }
    addout_k<<<2048, 256, 0, stream>>>(xf, dbuf, b2 + 7 * 512, (float*)d_out);
}

// Round 2
// 1358.219 us; speedup vs baseline: 1.0220x; 1.0220x over previous
//
#include <hip/hip_runtime.h>
#include <hip/hip_bf16.h>
#include <math.h>

typedef __bf16 bf16;
typedef __bf16 bf16x8 __attribute__((ext_vector_type(8)));
typedef __bf16 bf16x4 __attribute__((ext_vector_type(4)));
typedef float  f32x4  __attribute__((ext_vector_type(4)));

#define DEV __device__ __forceinline__

DEV f32x4 mfma16(bf16x8 a, bf16x8 b, f32x4 c) {
    return __builtin_amdgcn_mfma_f32_16x16x32_bf16(a, b, c, 0, 0, 0);
}

// async 16B global->LDS. LDS dest is wave-uniform base + lane*16 (linear!).
DEV void gload16(const bf16* g, bf16* l) {
    __builtin_amdgcn_global_load_lds(
        (const __attribute__((address_space(1))) void*)g,
        (__attribute__((address_space(3))) void*)l, 16, 0, 0);
}

// exact-enough erf: Abramowitz-Stegun 7.1.26, |err| <= 1.5e-7 (<< bf16 ulp)
DEV float gelu_f(float v) {
    float xs = v * 0.70710678118654752f;
    float ax = fabsf(xs);
    float t  = 1.0f / (1.0f + 0.3275911f * ax);
    float p  = t * (0.254829592f + t * (-0.284496736f + t * (1.421413741f +
               t * (-1.453152027f + t * 1.061405429f))));
    float er = 1.0f - p * __expf(-ax * ax);
    er = copysignf(er, xs);
    return 0.5f * v * (1.0f + er);
}

// ---------------------------------------------------------------------------
// Wide GEMM: C[M x N] = A[M x K] @ Bt[N x K]^T (+fp32 bias), 128x128, BK=32,
// double-buffered LDS + single barrier per K-step; global_load_lds width=16
// with chunk-XOR swizzle pre-applied to the GLOBAL source (both-sides rule).
// MODE 1: Cb = gelu(acc + bias).
// MODE 2 (QKV): cols <1024 (Q,K) -> Cb[ldC]; V tiles (tn>=1024) -> vt in
//   [(b*8+h)*64+d][n] layout via LDS transpose (coalesced 16B stores).
// ---------------------------------------------------------------------------
template <int MODE>
__global__ __launch_bounds__(256, 3) void gemm_k(
    const bf16* __restrict__ A, const bf16* __restrict__ Bt,
    const float* __restrict__ bias, bf16* __restrict__ Cb,
    bf16* __restrict__ vt, int K, int ldC)
{
    // dbuf: As0|As1|Bs0|Bs1 (4096 elems each). MODE2 epilogue reuses as
    // Ct[128 cols][136 rows] (17408 elems).
    __shared__ bf16 smem[(MODE == 2) ? 17408 : 16384];
    bf16* As = smem;            // [2][4096]
    bf16* Bs = smem + 8192;     // [2][4096]

    const int tid  = threadIdx.x;
    const int lane = tid & 63;
    const int w    = tid >> 6;
    const int wm   = w & 1, wn = w >> 1;
    const long tm  = (long)blockIdx.y * 128;
    const long tn  = (long)blockIdx.x * 128;

    f32x4 acc[4][4] = {};

    const int r0 = tid >> 2;
    const int cc = ((tid & 3) ^ ((r0 >> 1) & 3)) * 8;
    const bf16* Ag = A  + (tm + r0) * K + cc;
    const bf16* Bg = Bt + (tn + r0) * K + cc;
    const long rstep = (long)64 * K;

    int am[4], bn[4];
#pragma unroll
    for (int i = 0; i < 4; ++i) {
        int ra = wm * 64 + i * 16 + (lane & 15);
        am[i]  = ra * 32 + (((lane >> 4) ^ ((ra >> 1) & 3)) * 8);
        int rb = wn * 64 + i * 16 + (lane & 15);
        bn[i]  = rb * 32 + (((lane >> 4) ^ ((rb >> 1) & 3)) * 8);
    }

#define STAGE(buf, kk)                                        \
    do {                                                      \
        gload16(Ag + (kk),         &As[(buf)*4096 + tid*8]);  \
        gload16(Ag + rstep + (kk), &As[(buf)*4096 + 2048 + tid*8]); \
        gload16(Bg + (kk),         &Bs[(buf)*4096 + tid*8]);  \
        gload16(Bg + rstep + (kk), &Bs[(buf)*4096 + 2048 + tid*8]); \
    } while (0)

#define COMPUTE(buf)                                                    \
    do {                                                                \
        bf16x8 a[4], b[4];                                              \
        _Pragma("unroll")                                               \
        for (int i = 0; i < 4; ++i) a[i] = *(const bf16x8*)&As[(buf)*4096 + am[i]]; \
        _Pragma("unroll")                                               \
        for (int i = 0; i < 4; ++i) b[i] = *(const bf16x8*)&Bs[(buf)*4096 + bn[i]]; \
        _Pragma("unroll")                                               \
        for (int mi = 0; mi < 4; ++mi)                                  \
            _Pragma("unroll")                                           \
            for (int ni = 0; ni < 4; ++ni)                              \
                acc[mi][ni] = mfma16(a[mi], b[ni], acc[mi][ni]);        \
    } while (0)

    STAGE(0, 0);
    __syncthreads();
    for (int k0 = 0; k0 < K; k0 += 64) {     // K multiple of 64 in all uses
        STAGE(1, k0 + 32);
        COMPUTE(0);
        __syncthreads();
        if (k0 + 64 < K) STAGE(0, k0 + 64);
        COMPUTE(1);
        __syncthreads();
    }

    bool vpath = false;
    if constexpr (MODE == 2) vpath = (tn >= 1024);

    if (vpath) {
        // --- V tile: LDS transpose -> coalesced vt stores ---
        bf16* Ct = smem;  // [128 cols][136 rows]
#pragma unroll
        for (int mi = 0; mi < 4; ++mi) {
            const int rowL = wm * 64 + mi * 16 + ((lane >> 4) << 2);
#pragma unroll
            for (int ni = 0; ni < 4; ++ni) {
                const int colL = wn * 64 + ni * 16 + (lane & 15);
                const float bv = bias[tn + colL];
                bf16x4 pk;
#pragma unroll
                for (int r = 0; r < 4; ++r) pk[r] = (bf16)(acc[mi][ni][r] + bv);
                *(bf16x4*)&Ct[colL * 136 + rowL] = pk;
            }
        }
        __syncthreads();
        const int b_blk = (int)(tm >> 8);
        const int nin   = (int)(tm & 255);
        const int cvb   = (int)(tn - 1024);
#pragma unroll
        for (int j = 0; j < 8; ++j) {
            int idx = j * 256 + tid;          // 0..2047
            int c   = idx >> 4;               // 0..127
            int nc  = (idx & 15) * 8;         // 0..120
            bf16x8 vv = *(const bf16x8*)&Ct[c * 136 + nc];
            int cv = cvb + c;
            *(bf16x8*)&vt[(((long)b_blk * 8 + (cv >> 6)) * 64 + (cv & 63)) * 256 + nin + nc] = vv;
        }
        return;
    }

#pragma unroll
    for (int mi = 0; mi < 4; ++mi) {
        const long rbase = tm + wm * 64 + mi * 16 + ((lane >> 4) << 2);
#pragma unroll
        for (int ni = 0; ni < 4; ++ni) {
            const long col = tn + wn * 64 + ni * 16 + (lane & 15);
            const float bv = bias[col];
#pragma unroll
            for (int r = 0; r < 4; ++r) {
                float v = acc[mi][ni][r] + bv;
                if constexpr (MODE == 1) v = gelu_f(v);
                Cb[(rbase + r) * (long)ldC + col] = (bf16)v;
            }
        }
    }
#undef STAGE
#undef COMPUTE
}

// ---------------------------------------------------------------------------
// Split-K delta GEMM for proj/FFN2 (N=512): same dbuf single-barrier loop.
// ---------------------------------------------------------------------------
__global__ __launch_bounds__(256, 3) void gemm_dk(
    const bf16* __restrict__ A, const bf16* __restrict__ Bt,
    bf16* __restrict__ D, int K, int Ks)
{
    __shared__ bf16 smem[16384];
    bf16* As = smem;
    bf16* Bs = smem + 8192;

    const int tid  = threadIdx.x;
    const int lane = tid & 63;
    const int w    = tid >> 6;
    const int wm   = w & 1, wn = w >> 1;
    const long tm  = (long)blockIdx.y * 128;
    const long tn  = (long)blockIdx.x * 128;
    const int kbase = blockIdx.z * Ks;

    f32x4 acc[4][4] = {};

    const int r0 = tid >> 2;
    const int cc = ((tid & 3) ^ ((r0 >> 1) & 3)) * 8;
    const bf16* Ag = A  + (tm + r0) * K + kbase + cc;
    const bf16* Bg = Bt + (tn + r0) * K + kbase + cc;
    const long rstep = (long)64 * K;

    int am[4], bn[4];
#pragma unroll
    for (int i = 0; i < 4; ++i) {
        int ra = wm * 64 + i * 16 + (lane & 15);
        am[i]  = ra * 32 + (((lane >> 4) ^ ((ra >> 1) & 3)) * 8);
        int rb = wn * 64 + i * 16 + (lane & 15);
        bn[i]  = rb * 32 + (((lane >> 4) ^ ((rb >> 1) & 3)) * 8);
    }

#define STAGE(buf, kk)                                        \
    do {                                                      \
        gload16(Ag + (kk),         &As[(buf)*4096 + tid*8]);  \
        gload16(Ag + rstep + (kk), &As[(buf)*4096 + 2048 + tid*8]); \
        gload16(Bg + (kk),         &Bs[(buf)*4096 + tid*8]);  \
        gload16(Bg + rstep + (kk), &Bs[(buf)*4096 + 2048 + tid*8]); \
    } while (0)

#define COMPUTE(buf)                                                    \
    do {                                                                \
        bf16x8 a[4], b[4];                                              \
        _Pragma("unroll")                                               \
        for (int i = 0; i < 4; ++i) a[i] = *(const bf16x8*)&As[(buf)*4096 + am[i]]; \
        _Pragma("unroll")                                               \
        for (int i = 0; i < 4; ++i) b[i] = *(const bf16x8*)&Bs[(buf)*4096 + bn[i]]; \
        _Pragma("unroll")                                               \
        for (int mi = 0; mi < 4; ++mi)                                  \
            _Pragma("unroll")                                           \
            for (int ni = 0; ni < 4; ++ni)                              \
                acc[mi][ni] = mfma16(a[mi], b[ni], acc[mi][ni]);        \
    } while (0)

    STAGE(0, 0);
    __syncthreads();
    for (int k0 = 0; k0 < Ks; k0 += 64) {    // Ks multiple of 64 in all uses
        STAGE(1, k0 + 32);
        COMPUTE(0);
        __syncthreads();
        if (k0 + 64 < Ks) STAGE(0, k0 + 64);
        COMPUTE(1);
        __syncthreads();
    }

    bf16* Dp = D + (long)blockIdx.z * 8192 * 512;
#pragma unroll
    for (int mi = 0; mi < 4; ++mi) {
        const long rbase = tm + wm * 64 + mi * 16 + ((lane >> 4) << 2);
#pragma unroll
        for (int ni = 0; ni < 4; ++ni) {
            const long col = tn + wn * 64 + ni * 16 + (lane & 15);
#pragma unroll
            for (int r = 0; r < 4; ++r)
                Dp[(rbase + r) * 512 + col] = (bf16)acc[mi][ni][r];
        }
    }
#undef STAGE
#undef COMPUTE
}

// ---------------------------------------------------------------------------
// Attention: one block per (b, h, 64-row q tile). V from pre-transposed vt.
// ---------------------------------------------------------------------------
__global__ __launch_bounds__(256, 4) void attn_k(
    const bf16* __restrict__ qkv, const bf16* __restrict__ vt,
    const float* __restrict__ bias, bf16* __restrict__ ctx)
{
    __shared__ bf16 smem[256 * 72];
    bf16* Ks = smem;

    const int tid = threadIdx.x, lane = tid & 63, w = tid >> 6;
    const int qt = blockIdx.x & 3;
    const int h  = (blockIdx.x >> 2) & 7;
    const int b  = blockIdx.x >> 5;
    const long qkv_base = (long)b * 256 * 1536;

#pragma unroll
    for (int i = 0; i < 8; ++i) {
        int p = i * 256 + tid;
        int n = p >> 3, kk = (p & 7) * 8;
        uint4 v = *(const uint4*)(qkv + qkv_base + (long)n * 1536 + 512 + h * 64 + kk);
        *(uint4*)&Ks[n * 72 + kk] = v;
    }

    const int qr0 = qt * 64 + w * 16;
    bf16x8 aq0, aq1;
    {
        const bf16* g = qkv + qkv_base + (long)(qr0 + (lane & 15)) * 1536 + h * 64 + ((lane >> 4) * 8);
        aq0 = *(const bf16x8*)g;
        aq1 = *(const bf16x8*)(g + 32);
    }
    __syncthreads();

    f32x4 s[16];
    const float* bb = bias + (((long)(b * 8 + h)) * 256 + qr0) * 256;
#pragma unroll
    for (int ct = 0; ct < 16; ++ct) {
        const int col = ct * 16 + (lane & 15);
        f32x4 c;
#pragma unroll
        for (int r = 0; r < 4; ++r)
            c[r] = bb[(long)((lane >> 4) * 4 + r) * 256 + col];
        bf16x8 k0 = *(const bf16x8*)&Ks[(ct * 16 + (lane & 15)) * 72 + ((lane >> 4) * 8)];
        bf16x8 k1 = *(const bf16x8*)&Ks[(ct * 16 + (lane & 15)) * 72 + 32 + ((lane >> 4) * 8)];
        c = mfma16(aq0, k0, c);
        c = mfma16(aq1, k1, c);
        s[ct] = c;
    }

    float m[4] = {-1e30f, -1e30f, -1e30f, -1e30f};
#pragma unroll
    for (int ct = 0; ct < 16; ++ct)
#pragma unroll
        for (int r = 0; r < 4; ++r) m[r] = fmaxf(m[r], s[ct][r]);
#pragma unroll
    for (int r = 0; r < 4; ++r)
#pragma unroll
        for (int off = 1; off < 16; off <<= 1)
            m[r] = fmaxf(m[r], __shfl_xor(m[r], off));
    float l[4] = {0.f, 0.f, 0.f, 0.f};
#pragma unroll
    for (int ct = 0; ct < 16; ++ct)
#pragma unroll
        for (int r = 0; r < 4; ++r) {
            float p = __expf(s[ct][r] - m[r]);
            s[ct][r] = p;
            l[r] += p;
        }
#pragma unroll
    for (int r = 0; r < 4; ++r) {
#pragma unroll
        for (int off = 1; off < 16; off <<= 1) l[r] += __shfl_xor(l[r], off);
        l[r] = 1.0f / l[r];
    }

    __syncthreads();
    bf16* P = smem + w * (16 * 264);
#pragma unroll
    for (int ct = 0; ct < 16; ++ct)
#pragma unroll
        for (int r = 0; r < 4; ++r)
            P[(long)((lane >> 4) * 4 + r) * 264 + ct * 16 + (lane & 15)] = (bf16)s[ct][r];

    bf16x8 ap[8];
#pragma unroll
    for (int nk = 0; nk < 8; ++nk)
        ap[nk] = *(const bf16x8*)&P[(lane & 15) * 264 + nk * 32 + (lane >> 4) * 8];

    const bf16* vg = vt + (long)(b * 8 + h) * 64 * 256;
    f32x4 o[4];
#pragma unroll
    for (int dt = 0; dt < 4; ++dt) {
        f32x4 c = {};
#pragma unroll
        for (int nk = 0; nk < 8; ++nk) {
            bf16x8 bv = *(const bf16x8*)&vg[(dt * 16 + (lane & 15)) * 256 + nk * 32 + (lane >> 4) * 8];
            c = mfma16(ap[nk], bv, c);
        }
        o[dt] = c;
    }

#pragma unroll
    for (int dt = 0; dt < 4; ++dt) {
        const int col = h * 64 + dt * 16 + (lane & 15);
#pragma unroll
        for (int r = 0; r < 4; ++r) {
            const long row = (long)b * 256 + qr0 + (lane >> 4) * 4 + r;
            ctx[row * 512 + col] = (bf16)(o[dt][r] * l[r]);
        }
    }
}

// ---------------------------------------------------------------------------
// Fused residual-add + LayerNorm. NS = number of bf16 delta slices (0 or 2).
// ---------------------------------------------------------------------------
template <int NS>
__global__ __launch_bounds__(256) void ln_k(
    const float* __restrict__ x, float* __restrict__ xout,
    const bf16* __restrict__ d, const float* __restrict__ rbias,
    const float* __restrict__ sc, const float* __restrict__ bi,
    bf16* __restrict__ y)
{
    const int lane = threadIdx.x & 63;
    const long row = (long)blockIdx.x * 4 + (threadIdx.x >> 6);
    const float* xr = x + row * 512;
    float v[8];
    *(float4*)&v[0] = ((const float4*)xr)[lane * 2];
    *(float4*)&v[4] = ((const float4*)xr)[lane * 2 + 1];
    if constexpr (NS == 2) {
        bf16x8 d0 = *(const bf16x8*)&d[row * 512 + lane * 8];
        bf16x8 d1 = *(const bf16x8*)&d[(long)8192 * 512 + row * 512 + lane * 8];
        float b4[8];
        *(float4*)&b4[0] = ((const float4*)rbias)[lane * 2];
        *(float4*)&b4[4] = ((const float4*)rbias)[lane * 2 + 1];
#pragma unroll
        for (int j = 0; j < 8; ++j)
            v[j] += (float)d0[j] + (float)d1[j] + b4[j];
        float* xo = xout + row * 512;
        ((float4*)xo)[lane * 2]     = *(const float4*)&v[0];
        ((float4*)xo)[lane * 2 + 1] = *(const float4*)&v[4];
    }
    float sum = 0.f;
#pragma unroll
    for (int j = 0; j < 8; ++j) sum += v[j];
#pragma unroll
    for (int off = 1; off < 64; off <<= 1) sum += __shfl_xor(sum, off);
    const float mu = sum * (1.0f / 512.0f);
    float sq = 0.f;
#pragma unroll
    for (int j = 0; j < 8; ++j) { float dd = v[j] - mu; sq += dd * dd; }
#pragma unroll
    for (int off = 1; off < 64; off <<= 1) sq += __shfl_xor(sq, off);
    const float rs = rsqrtf(sq * (1.0f / 512.0f) + 1e-5f);
    bf16* yr = y + row * 512;
#pragma unroll
    for (int j = 0; j < 8; ++j) {
        int c = lane * 8 + j;
        yr[c] = (bf16)((v[j] - mu) * rs * sc[c] + bi[c]);
    }
}

// final: out = xf + d0 + d1 + rbias (fp32)
__global__ __launch_bounds__(256) void addout_k(
    const float* __restrict__ x, const bf16* __restrict__ d,
    const float* __restrict__ rbias, float* __restrict__ out)
{
    const int lane = threadIdx.x & 63;
    const long row = (long)blockIdx.x * 4 + (threadIdx.x >> 6);
    float v[8];
    *(float4*)&v[0] = ((const float4*)(x + row * 512))[lane * 2];
    *(float4*)&v[4] = ((const float4*)(x + row * 512))[lane * 2 + 1];
    bf16x8 d0 = *(const bf16x8*)&d[row * 512 + lane * 8];
    bf16x8 d1 = *(const bf16x8*)&d[(long)8192 * 512 + row * 512 + lane * 8];
    float b4[8];
    *(float4*)&b4[0] = ((const float4*)rbias)[lane * 2];
    *(float4*)&b4[4] = ((const float4*)rbias)[lane * 2 + 1];
#pragma unroll
    for (int j = 0; j < 8; ++j)
        v[j] += (float)d0[j] + (float)d1[j] + b4[j];
    float* o = out + row * 512;
    ((float4*)o)[lane * 2]     = *(const float4*)&v[0];
    ((float4*)o)[lane * 2 + 1] = *(const float4*)&v[4];
}

// ---------------------------------------------------------------------------
// One-shot weight transpose fp32 -> bf16 [N][K] layout (q-scale folded).
// ---------------------------------------------------------------------------
__global__ __launch_bounds__(256) void transpose_k(
    const float* __restrict__ wq, const float* __restrict__ wk,
    const float* __restrict__ wv, const float* __restrict__ wo,
    const float* __restrict__ w1, const float* __restrict__ w2,
    bf16* __restrict__ qkvT, bf16* __restrict__ woT,
    bf16* __restrict__ w1T, bf16* __restrict__ w2T)
{
    __shared__ float tile[32][33];
    const int tid = threadIdx.x, tx = tid & 31, ty = tid >> 5;
    const int l = blockIdx.x / 3072;
    const int r = blockIdx.x % 3072;

    const float* In = nullptr;
    bf16* Out = nullptr;
    int Nd, tk, tn, rowOff = 0, ldO;
    float scale = 1.0f;
    if (r < 1024) {
        const int which = r >> 8, t = r & 255;
        tn = t >> 4; tk = t & 15; Nd = 512; ldO = 512;
        const long woff = (long)l * 512 * 512;
        if (which == 0)      { In = wq + woff; Out = qkvT + (long)l * 1536 * 512; rowOff = 0;    scale = 0.125f; }
        else if (which == 1) { In = wk + woff; Out = qkvT + (long)l * 1536 * 512; rowOff = 512;  }
        else if (which == 2) { In = wv + woff; Out = qkvT + (long)l * 1536 * 512; rowOff = 1024; }
        else                 { In = wo + woff; Out = woT + woff; }
    } else if (r < 2048) {
        const int t = r - 1024;
        tn = t >> 4; tk = t & 15; Nd = 2048; ldO = 512;
        In = w1 + (long)l * 512 * 2048; Out = w1T + (long)l * 2048 * 512;
    } else {
        const int t = r - 2048;
        tn = t & 15; tk = t >> 4; Nd = 512; ldO = 2048;
        In = w2 + (long)l * 2048 * 512; Out = w2T + (long)l * 512 * 2048;
    }
    const int gk = tk * 32, gn = tn * 32;
#pragma unroll
    for (int j = 0; j < 4; ++j) {
        int rr = ty + j * 8;
        tile[rr][tx] = In[(long)(gk + rr) * Nd + gn + tx] * scale;
    }
    __syncthreads();
#pragma unroll
    for (int j = 0; j < 4; ++j) {
        int rr = ty + j * 8;
        Out[(long)(rowOff + gn + rr) * ldO + gk + tx] = (bf16)tile[tx][rr];
    }
}

__global__ void biasq_k(const float* __restrict__ bq, const float* __restrict__ bk,
                        const float* __restrict__ bv, float* __restrict__ bqkv)
{
    int i = blockIdx.x * 256 + threadIdx.x;
    if (i >= 8 * 1536) return;
    int l = i / 1536, j = i % 1536;
    float v;
    if (j < 512)       v = bq[l * 512 + j] * 0.125f;
    else if (j < 1024) v = bk[l * 512 + j - 512];
    else               v = bv[l * 512 + j - 1024];
    bqkv[i] = v;
}

// ---------------------------------------------------------------------------
extern "C" void kernel_launch(void* const* d_in, const int* in_sizes, int n_in,
                              void* d_out, int out_size, void* d_ws, size_t ws_size,
                              hipStream_t stream)
{
    (void)in_sizes; (void)n_in; (void)out_size; (void)ws_size;
    const float* x    = (const float*)d_in[0];
    const float* ab   = (const float*)d_in[1];
    const float* ln1s = (const float*)d_in[2];
    const float* ln1b = (const float*)d_in[3];
    const float* wq   = (const float*)d_in[4];
    const float* bq   = (const float*)d_in[5];
    const float* wk   = (const float*)d_in[6];
    const float* bk   = (const float*)d_in[7];
    const float* wv   = (const float*)d_in[8];
    const float* bv   = (const float*)d_in[9];
    const float* wo   = (const float*)d_in[10];
    const float* bo   = (const float*)d_in[11];
    const float* ln2s = (const float*)d_in[12];
    const float* ln2b = (const float*)d_in[13];
    const float* w1   = (const float*)d_in[14];
    const float* b1   = (const float*)d_in[15];
    const float* w2   = (const float*)d_in[16];
    const float* b2   = (const float*)d_in[17];

    char* ws = (char*)d_ws;
    float* xf   = (float*)ws;
    bf16* y     = (bf16*)(ws + 16777216);
    bf16* ctx   = y;
    bf16* qkv   = (bf16*)(ws + 16777216 + 8388608);
    bf16* ffn   = qkv;
    bf16* vt    = qkv + (long)8192 * 1536;
    bf16* dbuf  = (bf16*)(ws + 16777216 + 8388608 + 33554432);
    bf16* wqkvT = dbuf + (long)2 * 8192 * 512;
    bf16* woT   = wqkvT + (long)8 * 1536 * 512;
    bf16* w1T   = woT + (long)8 * 512 * 512;
    bf16* w2T   = w1T + (long)8 * 2048 * 512;
    float* bqkv = (float*)(w2T + (long)8 * 512 * 2048);

    hipMemcpyAsync(xf, x, (size_t)8192 * 512 * 4, hipMemcpyDeviceToDevice, stream);
    transpose_k<<<24576, 256, 0, stream>>>(wq, wk, wv, wo, w1, w2, wqkvT, woT, w1T, w2T);
    biasq_k<<<48, 256, 0, stream>>>(bq, bk, bv, bqkv);

    for (int l = 0; l < 8; ++l) {
        if (l == 0)
            ln_k<0><<<2048, 256, 0, stream>>>(xf, nullptr, nullptr, nullptr,
                                              ln1s, ln1b, y);
        else
            ln_k<2><<<2048, 256, 0, stream>>>(xf, xf, dbuf, b2 + (l - 1) * 512,
                                              ln1s + l * 512, ln1b + l * 512, y);
        gemm_k<2><<<dim3(12, 64), 256, 0, stream>>>(
            y, wqkvT + (long)l * 1536 * 512, bqkv + l * 1536, qkv, vt, 512, 1536);
        attn_k<<<1024, 256, 0, stream>>>(qkv, vt, ab, ctx);
        gemm_dk<<<dim3(4, 64, 2), 256, 0, stream>>>(
            ctx, woT + (long)l * 512 * 512, dbuf, 512, 256);
        ln_k<2><<<2048, 256, 0, stream>>>(xf, xf, dbuf, bo + l * 512,
                                          ln2s + l * 512, ln2b + l * 512, y);
        gemm_k<1><<<dim3(16, 64), 256, 0, stream>>>(
            y, w1T + (long)l * 2048 * 512, b1 + l * 2048, ffn, nullptr, 512, 2048);
        gemm_dk<<<dim3(4, 64, 2), 256, 0, stream>>>(
            ffn, w2T + (long)l * 512 * 2048, dbuf, 2048, 1024);
    }
    addout_k<<<2048, 256, 0, stream>>>(xf, dbuf, b2 + 7 * 512, (float*)d_out);
}